// Round 2
// baseline (184.922 us; speedup 1.0000x reference)
//
#include <hip/hip_runtime.h>
#include <math.h>

// out[b,i,j,f] = min_{di,dj,c} ( x[b,i+di,j+dj,c] - W[di,dj,c,f] )
// x: (16,128,128,16) f32, W: (3,3,16,32) f32, out: (16,126,126,32) f32
//
// R15 = R14 with the cross-half merge fixed.
// R14 bug: inline asm "v_permlane32_swap_b32 %0,%1" with "+v"(ua),"+v"(ub)
// where ub was a copy of ua -- regalloc aliased both to ONE VGPR; a
// same-register swap destroys the own-half value (absmax 2.6).
// Fix: __builtin_amdgcn_permlane32_swap(a, a) returns an SSA PAIR {d0,d1}:
//   d0 = high-half broadcast into both halves, d1 = low-half broadcast,
//   so min(d0,d1)[lane] = min(own, partner) in every lane. Alias-proof,
//   direction-proof. Fallback: __shfl_xor(...,32).
//
// Structure (from R14):
//  * 512-thread blocks, 8 output cols (grid 16x6x16 = 1536 blocks):
//    halo 10 staged cols for 8 outputs, W restage amortized 2x vs R13.
//  * ONE __syncthreads() per block: tile + W LDS disjoint, read-only after.
//  * No vm-LDS epilogue: channel halves merged in-register (lane^32),
//    stored directly from the main loop (21 coalesced 128B half-wave stores
//    per wave).

#define TI 21           // output rows per block; 126 = 21*6
#define TROWS (TI + 2)  // input rows per tile (23)
#define NCOL 8          // output cols per block
#define SCOL 10         // staged cols (NCOL + 2 halo)
#define LROW 80         // tile row stride in halves (10 cols * 8 halves)

typedef _Float16 h2 __attribute__((ext_vector_type(2)));

__device__ __forceinline__ h2 hmin2(h2 a, h2 b) {
    return __builtin_elementwise_min(a, b);  // v_pk_min_f16
}

__device__ __forceinline__ h2 pkrtz(float a, float b) {
    auto r = __builtin_amdgcn_cvt_pkrtz(a, b);  // v_cvt_pkrtz_f16_f32
    return *reinterpret_cast<h2*>(&r);
}

// min over 12 half2 of (pr[k] - w[k]) for one weight row di; consumes the
// prefetch registers directly (SSA, no copies).
__device__ __forceinline__ h2 rowmin3(const float4* pr, const h2 w[3][4]) {
    h2 t[12];
#pragma unroll
    for (int dj = 0; dj < 3; ++dj) {
        const h2* p = reinterpret_cast<const h2*>(&pr[dj]);
#pragma unroll
        for (int q = 0; q < 4; ++q)
            t[dj * 4 + q] = p[q] - w[dj][q];  // v_pk_add_f16 neg
    }
#pragma unroll
    for (int k = 0; k < 6; ++k) t[k] = hmin2(t[k], t[k + 6]);
    t[0] = hmin2(t[0], t[3]);
    t[1] = hmin2(t[1], t[4]);
    t[2] = hmin2(t[2], t[5]);
    return hmin2(hmin2(t[0], t[1]), t[2]);
}

__global__ __launch_bounds__(512, 8) void erosion_kernel(
    const float* __restrict__ x, const float* __restrict__ Wt,
    float* __restrict__ out)
{
    __shared__ __align__(16) _Float16 tile[2 * TROWS * LROW];  // 7360 B
    __shared__ __align__(16) _Float16 wbuf[2 * 2304];          // 9216 B

    const int tid = threadIdx.x;
    const int f  = tid & 31;
    const int ch = (tid >> 5) & 1;   // channel half: 0 -> c 0..7, 1 -> c 8..15
    const int jt = tid >> 6;         // column in block 0..7 (wave-uniform)
    const int b  = blockIdx.z;
    const int i0 = blockIdx.y * TI;
    const int jb = blockIdx.x * NCOL;

    // ---- stage x tile: fp32 -> fp16 LDS (23 rows x 10 cols x 2 ch) ----
    // 460 chunks, one per thread (52 threads idle).
    if (tid < TROWS * 2 * SCOL) {
        const float* xg = x + (size_t)b * (128 * 128 * 16);
        int r   = tid / (2 * SCOL);
        int k   = tid % (2 * SCOL);
        int cc  = k >> 1;               // 0..9 tile column
        int ch2 = k & 1;
        int col = min(jb + cc, 127);    // clamp: feeds never-stored outputs only
        const float* src = xg + ((size_t)(i0 + r) * 128 + col) * 16 + ch2 * 8;
        float4 lo = *reinterpret_cast<const float4*>(src);
        float4 hi = *reinterpret_cast<const float4*>(src + 4);
        h2 o[4] = { pkrtz(lo.x, lo.y), pkrtz(lo.z, lo.w),
                    pkrtz(hi.x, hi.y), pkrtz(hi.z, hi.w) };
        *reinterpret_cast<float4*>(
            &tile[ch2 * (TROWS * LROW) + r * LROW + cc * 8]) =
            *reinterpret_cast<float4*>(o);
    }

    // ---- stage W packed-h2: wl[g*32 + f] = {W[.,2c,f],W[.,2c+1,f]} ----
    // g = p*8 + cpair (p = di*3+dj, cpair = c/2); W flat idx = g*64 + f.
    // 2304 h2 tasks = 4.5 rounds of 512.
    {
        h2* wl = reinterpret_cast<h2*>(wbuf);
#pragma unroll
        for (int rr = 0; rr < 4; ++rr) {
            int t  = rr * 512 + tid;
            int g  = t >> 5;
            int ff = t & 31;
            wl[t] = pkrtz(Wt[g * 64 + ff], Wt[g * 64 + 32 + ff]);
        }
        if (tid < 2304 - 2048) {
            int t  = 2048 + tid;
            int g  = t >> 5;
            int ff = t & 31;
            wl[t] = pkrtz(Wt[g * 64 + ff], Wt[g * 64 + 32 + ff]);
        }
    }

    __syncthreads();   // the only barrier: LDS read-only from here on

    // ---- read this thread's W frags: 36 conflict-free ds_read_b32 ----
    h2 wh[3][3][4];
    {
        const h2* wl = reinterpret_cast<const h2*>(wbuf);
#pragma unroll
        for (int p = 0; p < 9; ++p)
#pragma unroll
            for (int q = 0; q < 4; ++q)
                wh[p / 3][p % 3][q] = wl[(p * 8 + ch * 4 + q) * 32 + f];
    }

    const _Float16* lb = &tile[ch * (TROWS * LROW) + jt * 8];  // row 0, col jt

    // prime depth-1 prefetch regs
    float4 pre[3];
#pragma unroll
    for (int dj = 0; dj < 3; ++dj)
        pre[dj] = *reinterpret_cast<const float4*>(lb + dj * 8);

    const _Float16 HINF = (_Float16)__builtin_huge_valf();
    h2 accB = {HINF, HINF};  // partial min for output row r-1
    h2 accC = {HINF, HINF};  // partial min for output row r-2

    const int jj = jb + jt;
    const bool wr = (ch == 0) && (jj < 126);   // half-wave store mask
    float* outb = out + (size_t)b * (126 * 126 * 32) + (size_t)jj * 32 + f;

    auto body = [&](int r, bool do_prefetch, bool do_store) {
        h2 n0 = rowmin3(pre, wh[0]);
        h2 n1 = rowmin3(pre, wh[1]);
        h2 n2 = rowmin3(pre, wh[2]);

        if (do_prefetch) {
            const _Float16* ln = lb + (r + 1) * LROW;
#pragma unroll
            for (int dj = 0; dj < 3; ++dj)
                pre[dj] = *reinterpret_cast<const float4*>(ln + dj * 8);
        }

        h2 fin2 = hmin2(accC, n2);  // output row r-2 complete (this ch-half)
        accC = hmin2(accB, n1);
        accB = n0;

        if (do_store) {
            // cross-half merge: partner thread is lane^32 of the same wave.
            unsigned ua = __builtin_bit_cast(unsigned, fin2);
#if __has_builtin(__builtin_amdgcn_permlane32_swap)
            // {d0,d1} SSA pair: d0 = high-half bcast, d1 = low-half bcast
            // (both inputs identical), so min(d0,d1) = min(own, partner)
            // in every lane regardless of swap direction convention.
            auto sw = __builtin_amdgcn_permlane32_swap(ua, ua, false, false);
            h2 m2 = hmin2(__builtin_bit_cast(h2, (unsigned)sw[0]),
                          __builtin_bit_cast(h2, (unsigned)sw[1]));
#else
            unsigned ub = (unsigned)__shfl_xor((int)ua, 32, 64);
            h2 m2 = hmin2(fin2, __builtin_bit_cast(h2, ub));
#endif
            _Float16 m = m2[0] < m2[1] ? m2[0] : m2[1];   // v_min_f16
            if (wr)
                outb[(size_t)(i0 + r - 2) * (126 * 32)] = (float)m;
        }
    };

    body(0, true, false);
    body(1, true, false);
#pragma unroll
    for (int r = 2; r < TROWS - 1; ++r)   // FULL unroll: r = 2..21 literal
        body(r, true, true);
    body(TROWS - 1, false, true);         // r = 22, no prefetch
}

extern "C" void kernel_launch(void* const* d_in, const int* in_sizes, int n_in,
                              void* d_out, int out_size, void* d_ws, size_t ws_size,
                              hipStream_t stream) {
    const float* x  = (const float*)d_in[0];  // 16*128*128*16
    const float* Wt = (const float*)d_in[1];  // 3*3*16*32
    float* out = (float*)d_out;               // 16*126*126*32

    dim3 grid(16, 6, 16);   // 1536 blocks, 8 output cols each
    dim3 block(512);
    erosion_kernel<<<grid, block, 0, stream>>>(x, Wt, out);
}

// Round 3
// 174.153 us; speedup vs baseline: 1.0618x; 1.0618x over previous
//
#include <hip/hip_runtime.h>
#include <math.h>

// out[b,i,j,f] = min_{di,dj,c} ( x[b,i+di,j+dj,c] - W[di,dj,c,f] )
// x: (16,128,128,16) f32, W: (3,3,16,32) f32, out: (16,126,126,32) f32
//
// R16 = R15 structure with the store path fixed.
// R15 lesson (counters): direct half-wave 128B dword stores per row tripled
// HBM-side traffic (WRITE 31.7->80.9 MB, FETCH 12.4->33 MB: partial-line
// RMW at the TCC) and collapsed VALUBusy 66->28. Writes must be wide,
// fully-covering bursts: R13's merge epilogue measured WRITE == out size
// exactly with float4 stores (1KB contiguous per wave).
//
// Structure:
//  * 512-thread blocks, 8 output cols (grid 16x6x16 = 1536 blocks):
//    halo 10 staged cols for 8 outputs, W restage amortized 2x vs R13.
//  * tile + wbuf read-only after ONE staging barrier; vm is a separate
//    buffer (no overlay -> no extra barrier; 2 barriers total vs R13's 3).
//  * body: per-thread v_min_f16 -> full-wave b16 LDS write into vm
//    (LDS has no RMW penalty), ch-halves merged in the epilogue.
//  * epilogue: 1344 float4 tasks; each wave stores 1KB contiguous.
//  * vm col stride = 68 halves (8B-aligned) to spread the epilogue's
//    ds_read_b64 across banks (stride 64 would be a clean 8-way conflict).

#define TI 21           // output rows per block; 126 = 21*6
#define TROWS (TI + 2)  // input rows per tile (23)
#define NCOL 8          // output cols per block
#define SCOL 10         // staged cols (NCOL + 2 halo)
#define LROW 80         // tile row stride in halves (10 cols * 8 halves)
#define VCOL 68         // vm col stride in halves (64 used + 4 pad)
#define VROW (NCOL * VCOL)  // 544 halves per output row

typedef _Float16 h2 __attribute__((ext_vector_type(2)));

__device__ __forceinline__ h2 hmin2(h2 a, h2 b) {
    return __builtin_elementwise_min(a, b);  // v_pk_min_f16
}

__device__ __forceinline__ h2 pkrtz(float a, float b) {
    auto r = __builtin_amdgcn_cvt_pkrtz(a, b);  // v_cvt_pkrtz_f16_f32
    return *reinterpret_cast<h2*>(&r);
}

// min over 12 half2 of (pr[k] - w[k]) for one weight row di; consumes the
// prefetch registers directly (SSA, no copies).
__device__ __forceinline__ h2 rowmin3(const float4* pr, const h2 w[3][4]) {
    h2 t[12];
#pragma unroll
    for (int dj = 0; dj < 3; ++dj) {
        const h2* p = reinterpret_cast<const h2*>(&pr[dj]);
#pragma unroll
        for (int q = 0; q < 4; ++q)
            t[dj * 4 + q] = p[q] - w[dj][q];  // v_pk_add_f16 neg
    }
#pragma unroll
    for (int k = 0; k < 6; ++k) t[k] = hmin2(t[k], t[k + 6]);
    t[0] = hmin2(t[0], t[3]);
    t[1] = hmin2(t[1], t[4]);
    t[2] = hmin2(t[2], t[5]);
    return hmin2(hmin2(t[0], t[1]), t[2]);
}

__global__ __launch_bounds__(512, 8) void erosion_kernel(
    const float* __restrict__ x, const float* __restrict__ Wt,
    float* __restrict__ out)
{
    __shared__ __align__(16) _Float16 tile[2 * TROWS * LROW];  // 7360 B
    __shared__ __align__(16) _Float16 wbuf[2 * 2304];          // 9216 B
    __shared__ __align__(16) _Float16 vm[TI * VROW];           // 22848 B

    const int tid = threadIdx.x;
    const int f  = tid & 31;
    const int ch = (tid >> 5) & 1;   // channel half: 0 -> c 0..7, 1 -> c 8..15
    const int jt = tid >> 6;         // column in block 0..7 (wave-uniform)
    const int b  = blockIdx.z;
    const int i0 = blockIdx.y * TI;
    const int jb = blockIdx.x * NCOL;

    // ---- stage x tile: fp32 -> fp16 LDS (23 rows x 10 cols x 2 ch) ----
    // 460 chunks, one per thread (52 threads idle).
    if (tid < TROWS * 2 * SCOL) {
        const float* xg = x + (size_t)b * (128 * 128 * 16);
        int r   = tid / (2 * SCOL);
        int k   = tid % (2 * SCOL);
        int cc  = k >> 1;               // 0..9 tile column
        int ch2 = k & 1;
        int col = min(jb + cc, 127);    // clamp: feeds never-stored outputs only
        const float* src = xg + ((size_t)(i0 + r) * 128 + col) * 16 + ch2 * 8;
        float4 lo = *reinterpret_cast<const float4*>(src);
        float4 hi = *reinterpret_cast<const float4*>(src + 4);
        h2 o[4] = { pkrtz(lo.x, lo.y), pkrtz(lo.z, lo.w),
                    pkrtz(hi.x, hi.y), pkrtz(hi.z, hi.w) };
        *reinterpret_cast<float4*>(
            &tile[ch2 * (TROWS * LROW) + r * LROW + cc * 8]) =
            *reinterpret_cast<float4*>(o);
    }

    // ---- stage W packed-h2: wl[g*32 + f] = {W[.,2c,f],W[.,2c+1,f]} ----
    // g = p*8 + cpair (p = di*3+dj, cpair = c/2); W flat idx = g*64 + f.
    // 2304 h2 tasks = 4.5 rounds of 512.
    {
        h2* wl = reinterpret_cast<h2*>(wbuf);
#pragma unroll
        for (int rr = 0; rr < 4; ++rr) {
            int t  = rr * 512 + tid;
            int g  = t >> 5;
            int ff = t & 31;
            wl[t] = pkrtz(Wt[g * 64 + ff], Wt[g * 64 + 32 + ff]);
        }
        if (tid < 2304 - 2048) {
            int t  = 2048 + tid;
            int g  = t >> 5;
            int ff = t & 31;
            wl[t] = pkrtz(Wt[g * 64 + ff], Wt[g * 64 + 32 + ff]);
        }
    }

    __syncthreads();   // barrier 1: tile + wbuf read-only from here on

    // ---- read this thread's W frags: 36 conflict-free ds_read_b32 ----
    h2 wh[3][3][4];
    {
        const h2* wl = reinterpret_cast<const h2*>(wbuf);
#pragma unroll
        for (int p = 0; p < 9; ++p)
#pragma unroll
            for (int q = 0; q < 4; ++q)
                wh[p / 3][p % 3][q] = wl[(p * 8 + ch * 4 + q) * 32 + f];
    }

    const _Float16* lb = &tile[ch * (TROWS * LROW) + jt * 8];  // row 0, col jt

    // prime depth-1 prefetch regs
    float4 pre[3];
#pragma unroll
    for (int dj = 0; dj < 3; ++dj)
        pre[dj] = *reinterpret_cast<const float4*>(lb + dj * 8);

    const _Float16 HINF = (_Float16)__builtin_huge_valf();
    h2 accB = {HINF, HINF};  // partial min for output row r-1
    h2 accC = {HINF, HINF};  // partial min for output row r-2

    // vm slot for this thread: [row][jt][ch][f] with padded col stride
    _Float16* vslot = &vm[jt * VCOL + ch * 32 + f];

    auto body = [&](int r, bool do_prefetch, bool do_vm) {
        h2 n0 = rowmin3(pre, wh[0]);
        h2 n1 = rowmin3(pre, wh[1]);
        h2 n2 = rowmin3(pre, wh[2]);

        if (do_prefetch) {
            const _Float16* ln = lb + (r + 1) * LROW;
#pragma unroll
            for (int dj = 0; dj < 3; ++dj)
                pre[dj] = *reinterpret_cast<const float4*>(ln + dj * 8);
        }

        h2 fin2 = hmin2(accC, n2);  // output row r-2 complete (this ch-half)
        accC = hmin2(accB, n1);
        accB = n0;

        if (do_vm) {
            _Float16 a = fin2[0], c = fin2[1];
            _Float16 m = a < c ? a : c;          // v_min_f16
            vslot[(r - 2) * VROW] = m;           // full-wave b16 LDS write
        }
    };

    body(0, true, false);
    body(1, true, false);
#pragma unroll
    for (int r = 2; r < TROWS - 1; ++r)   // FULL unroll: r = 2..21 literal
        body(r, true, true);
    body(TROWS - 1, false, true);         // r = 22, no prefetch

    __syncthreads();   // barrier 2: vm complete

    // ---- merge epilogue: 1344 float4 tasks, 1KB contiguous per wave ----
    // task t: row = t>>6, k = t&63, col = k>>3, q = k&7.
    // partials: ch0 at vm[row*VROW + col*VCOL + 4q..+3], ch1 at +32.
    {
        float* outb = out + (size_t)b * (126 * 126 * 32);
        auto merge = [&](int t) {
            int row = t >> 6;
            int k   = t & 63;
            int col = k >> 3;
            int q   = k & 7;
            int jj  = jb + col;
            const _Float16* base = &vm[row * VROW + col * VCOL + q * 4];
            h2 a[2], c[2];
            *reinterpret_cast<double*>(a) = *reinterpret_cast<const double*>(base);
            *reinterpret_cast<double*>(c) = *reinterpret_cast<const double*>(base + 32);
            h2 m0 = hmin2(a[0], c[0]);
            h2 m1 = hmin2(a[1], c[1]);
            float4 o = { (float)m0[0], (float)m0[1], (float)m1[0], (float)m1[1] };
            if (jj < 126)
                *reinterpret_cast<float4*>(
                    &outb[((size_t)(i0 + row) * 126 + jj) * 32 + q * 4]) = o;
        };
        merge(tid);
        merge(tid + 512);
        if (tid < TI * 64 - 1024) merge(tid + 1024);  // 320 extra tasks
    }
}

extern "C" void kernel_launch(void* const* d_in, const int* in_sizes, int n_in,
                              void* d_out, int out_size, void* d_ws, size_t ws_size,
                              hipStream_t stream) {
    const float* x  = (const float*)d_in[0];  // 16*128*128*16
    const float* Wt = (const float*)d_in[1];  // 3*3*16*32
    float* out = (float*)d_out;               // 16*126*126*32

    dim3 grid(16, 6, 16);   // 1536 blocks, 8 output cols each
    dim3 block(512);
    erosion_kernel<<<grid, block, 0, stream>>>(x, Wt, out);
}

// Round 4
// 107.669 us; speedup vs baseline: 1.7175x; 1.6175x over previous
//
#include <hip/hip_runtime.h>
#include <math.h>

// out[b,i,j,f] = min_{di,dj,c} ( x[b,i+di,j+dj,c] - W[di,dj,c,f] )
// x: (16,128,128,16) f32, W: (3,3,16,32) f32, out: (16,126,126,32) f32
//
// R17 = R16 with the REAL bug fixed: __launch_bounds__(512,8) capped VGPRs
// at 64 (compiler hit 32) -> wh[3][3][4] (36 dwords/thread) SPILLED TO
// SCRATCH. Counters: ~165 B/thread excess fetch + ~168 B/thread excess
// write (146/164 MB per dispatch) == one wh spill+reload; VALUBusy 30%.
// Fix: __launch_bounds__(512,4) -> VGPR cap 128, wh/pre/acc register-
// resident. 4 waves/EU x 4 EU = 2 blocks/CU (LDS 39.4KB also allows it),
// 50% occupancy = R13's measured level.
//
// Structure (unchanged from R16):
//  * 512-thread blocks, 8 output cols (grid 16x6x16 = 1536 blocks):
//    halo 10 staged cols for 8 outputs, W restage amortized 2x vs R13.
//  * tile + wbuf read-only after ONE staging barrier; vm separate buffer
//    (2 barriers total vs R13's 3).
//  * body: per-thread v_min_f16 -> full-wave b16 LDS write into vm,
//    ch-halves merged in the epilogue.
//  * epilogue: 1344 float4 tasks; each wave stores 1KB contiguous
//    (R13-proven: WRITE_SIZE == out size exactly; R15's narrow direct
//    stores caused 2.5x RMW write amplification).

#define TI 21           // output rows per block; 126 = 21*6
#define TROWS (TI + 2)  // input rows per tile (23)
#define NCOL 8          // output cols per block
#define SCOL 10         // staged cols (NCOL + 2 halo)
#define LROW 80         // tile row stride in halves (10 cols * 8 halves)
#define VCOL 68         // vm col stride in halves (64 used + 4 pad)
#define VROW (NCOL * VCOL)  // 544 halves per output row

typedef _Float16 h2 __attribute__((ext_vector_type(2)));

__device__ __forceinline__ h2 hmin2(h2 a, h2 b) {
    return __builtin_elementwise_min(a, b);  // v_pk_min_f16
}

__device__ __forceinline__ h2 pkrtz(float a, float b) {
    auto r = __builtin_amdgcn_cvt_pkrtz(a, b);  // v_cvt_pkrtz_f16_f32
    return *reinterpret_cast<h2*>(&r);
}

// min over 12 half2 of (pr[k] - w[k]) for one weight row di; consumes the
// prefetch registers directly (SSA, no copies).
__device__ __forceinline__ h2 rowmin3(const float4* pr, const h2 w[3][4]) {
    h2 t[12];
#pragma unroll
    for (int dj = 0; dj < 3; ++dj) {
        const h2* p = reinterpret_cast<const h2*>(&pr[dj]);
#pragma unroll
        for (int q = 0; q < 4; ++q)
            t[dj * 4 + q] = p[q] - w[dj][q];  // v_pk_add_f16 neg
    }
#pragma unroll
    for (int k = 0; k < 6; ++k) t[k] = hmin2(t[k], t[k + 6]);
    t[0] = hmin2(t[0], t[3]);
    t[1] = hmin2(t[1], t[4]);
    t[2] = hmin2(t[2], t[5]);
    return hmin2(hmin2(t[0], t[1]), t[2]);
}

__global__ __launch_bounds__(512, 4) void erosion_kernel(
    const float* __restrict__ x, const float* __restrict__ Wt,
    float* __restrict__ out)
{
    __shared__ __align__(16) _Float16 tile[2 * TROWS * LROW];  // 7360 B
    __shared__ __align__(16) _Float16 wbuf[2 * 2304];          // 9216 B
    __shared__ __align__(16) _Float16 vm[TI * VROW];           // 22848 B

    const int tid = threadIdx.x;
    const int f  = tid & 31;
    const int ch = (tid >> 5) & 1;   // channel half: 0 -> c 0..7, 1 -> c 8..15
    const int jt = tid >> 6;         // column in block 0..7 (wave-uniform)
    const int b  = blockIdx.z;
    const int i0 = blockIdx.y * TI;
    const int jb = blockIdx.x * NCOL;

    // ---- stage x tile: fp32 -> fp16 LDS (23 rows x 10 cols x 2 ch) ----
    // 460 chunks, one per thread (52 threads idle).
    if (tid < TROWS * 2 * SCOL) {
        const float* xg = x + (size_t)b * (128 * 128 * 16);
        int r   = tid / (2 * SCOL);
        int k   = tid % (2 * SCOL);
        int cc  = k >> 1;               // 0..9 tile column
        int ch2 = k & 1;
        int col = min(jb + cc, 127);    // clamp: feeds never-stored outputs only
        const float* src = xg + ((size_t)(i0 + r) * 128 + col) * 16 + ch2 * 8;
        float4 lo = *reinterpret_cast<const float4*>(src);
        float4 hi = *reinterpret_cast<const float4*>(src + 4);
        h2 o[4] = { pkrtz(lo.x, lo.y), pkrtz(lo.z, lo.w),
                    pkrtz(hi.x, hi.y), pkrtz(hi.z, hi.w) };
        *reinterpret_cast<float4*>(
            &tile[ch2 * (TROWS * LROW) + r * LROW + cc * 8]) =
            *reinterpret_cast<float4*>(o);
    }

    // ---- stage W packed-h2: wl[g*32 + f] = {W[.,2c,f],W[.,2c+1,f]} ----
    // g = p*8 + cpair (p = di*3+dj, cpair = c/2); W flat idx = g*64 + f.
    // 2304 h2 tasks = 4.5 rounds of 512.
    {
        h2* wl = reinterpret_cast<h2*>(wbuf);
#pragma unroll
        for (int rr = 0; rr < 4; ++rr) {
            int t  = rr * 512 + tid;
            int g  = t >> 5;
            int ff = t & 31;
            wl[t] = pkrtz(Wt[g * 64 + ff], Wt[g * 64 + 32 + ff]);
        }
        if (tid < 2304 - 2048) {
            int t  = 2048 + tid;
            int g  = t >> 5;
            int ff = t & 31;
            wl[t] = pkrtz(Wt[g * 64 + ff], Wt[g * 64 + 32 + ff]);
        }
    }

    __syncthreads();   // barrier 1: tile + wbuf read-only from here on

    // ---- read this thread's W frags: 36 conflict-free ds_read_b32 ----
    h2 wh[3][3][4];
    {
        const h2* wl = reinterpret_cast<const h2*>(wbuf);
#pragma unroll
        for (int p = 0; p < 9; ++p)
#pragma unroll
            for (int q = 0; q < 4; ++q)
                wh[p / 3][p % 3][q] = wl[(p * 8 + ch * 4 + q) * 32 + f];
    }

    const _Float16* lb = &tile[ch * (TROWS * LROW) + jt * 8];  // row 0, col jt

    // prime depth-1 prefetch regs
    float4 pre[3];
#pragma unroll
    for (int dj = 0; dj < 3; ++dj)
        pre[dj] = *reinterpret_cast<const float4*>(lb + dj * 8);

    const _Float16 HINF = (_Float16)__builtin_huge_valf();
    h2 accB = {HINF, HINF};  // partial min for output row r-1
    h2 accC = {HINF, HINF};  // partial min for output row r-2

    // vm slot for this thread: [row][jt][ch][f] with padded col stride
    _Float16* vslot = &vm[jt * VCOL + ch * 32 + f];

    auto body = [&](int r, bool do_prefetch, bool do_vm) {
        h2 n0 = rowmin3(pre, wh[0]);
        h2 n1 = rowmin3(pre, wh[1]);
        h2 n2 = rowmin3(pre, wh[2]);

        if (do_prefetch) {
            const _Float16* ln = lb + (r + 1) * LROW;
#pragma unroll
            for (int dj = 0; dj < 3; ++dj)
                pre[dj] = *reinterpret_cast<const float4*>(ln + dj * 8);
        }

        h2 fin2 = hmin2(accC, n2);  // output row r-2 complete (this ch-half)
        accC = hmin2(accB, n1);
        accB = n0;

        if (do_vm) {
            _Float16 a = fin2[0], c = fin2[1];
            _Float16 m = a < c ? a : c;          // v_min_f16
            vslot[(r - 2) * VROW] = m;           // full-wave b16 LDS write
        }
    };

    body(0, true, false);
    body(1, true, false);
#pragma unroll
    for (int r = 2; r < TROWS - 1; ++r)   // FULL unroll: r = 2..21 literal
        body(r, true, true);
    body(TROWS - 1, false, true);         // r = 22, no prefetch

    __syncthreads();   // barrier 2: vm complete

    // ---- merge epilogue: 1344 float4 tasks, 1KB contiguous per wave ----
    // task t: row = t>>6, k = t&63, col = k>>3, q = k&7.
    // partials: ch0 at vm[row*VROW + col*VCOL + 4q..+3], ch1 at +32.
    {
        float* outb = out + (size_t)b * (126 * 126 * 32);
        auto merge = [&](int t) {
            int row = t >> 6;
            int k   = t & 63;
            int col = k >> 3;
            int q   = k & 7;
            int jj  = jb + col;
            const _Float16* base = &vm[row * VROW + col * VCOL + q * 4];
            h2 a[2], c[2];
            *reinterpret_cast<double*>(a) = *reinterpret_cast<const double*>(base);
            *reinterpret_cast<double*>(c) = *reinterpret_cast<const double*>(base + 32);
            h2 m0 = hmin2(a[0], c[0]);
            h2 m1 = hmin2(a[1], c[1]);
            float4 o = { (float)m0[0], (float)m0[1], (float)m1[0], (float)m1[1] };
            if (jj < 126)
                *reinterpret_cast<float4*>(
                    &outb[((size_t)(i0 + row) * 126 + jj) * 32 + q * 4]) = o;
        };
        merge(tid);
        merge(tid + 512);
        if (tid < TI * 64 - 1024) merge(tid + 1024);  // 320 extra tasks
    }
}

extern "C" void kernel_launch(void* const* d_in, const int* in_sizes, int n_in,
                              void* d_out, int out_size, void* d_ws, size_t ws_size,
                              hipStream_t stream) {
    const float* x  = (const float*)d_in[0];  // 16*128*128*16
    const float* Wt = (const float*)d_in[1];  // 3*3*16*32
    float* out = (float*)d_out;               // 16*126*126*32

    dim3 grid(16, 6, 16);   // 1536 blocks, 8 output cols each
    dim3 block(512);
    erosion_kernel<<<grid, block, 0, stream>>>(x, Wt, out);
}

// Round 5
// 107.051 us; speedup vs baseline: 1.7274x; 1.0058x over previous
//
#include <hip/hip_runtime.h>
#include <math.h>

// out[b,i,j,f] = min_{di,dj,c} ( x[b,i+di,j+dj,c] - W[di,dj,c,f] )
// x: (16,128,128,16) f32, W: (3,3,16,32) f32, out: (16,126,126,32) f32
//
// R18 = R17 + forced register residency for wh.
// R17 post-mortem: VGPR_Count=36 with no scratch -> the compiler SANK the
// 36 wh ds_read_b32 into the unrolled main loop (wbuf provably constant
// after barrier 1, so rematerializing beats keeping 36 regs live).
// Cost: 23 bodies x (36 b32 + 3 b128) = 4.4 KB LDS reads/thread = 3.47 GB
// total = 44 us at the 78 TB/s LDS ceiling == the measured 47.8 us.
// Kernel was LDS-READ-THROUGHPUT-bound on redundant W reads.
// Fix: empty inline-asm value capture (asm "" : "+v") after the one-time
// wh read -- values become opaque SSA defs, not rematerializable. VGPR
// should jump to ~90-110 (cap 128 via __launch_bounds__(512,4)); main-loop
// LDS traffic drops 4x; VALU issue (~17-20 us) becomes the binding pipe.
//
// Structure (unchanged from R17):
//  * 512-thread blocks, 8 output cols (grid 16x6x16 = 1536 blocks).
//  * tile + wbuf read-only after ONE staging barrier; vm separate buffer.
//  * body: rolling 3-row window, packed-h2 min core, full-wave b16 vm
//    writes; ch-halves merged in float4 epilogue (WRITE == out size,
//    R15 lesson: never narrow-store to HBM).

#define TI 21           // output rows per block; 126 = 21*6
#define TROWS (TI + 2)  // input rows per tile (23)
#define NCOL 8          // output cols per block
#define SCOL 10         // staged cols (NCOL + 2 halo)
#define LROW 80         // tile row stride in halves (10 cols * 8 halves)
#define VCOL 68         // vm col stride in halves (64 used + 4 pad)
#define VROW (NCOL * VCOL)  // 544 halves per output row

typedef _Float16 h2 __attribute__((ext_vector_type(2)));

__device__ __forceinline__ h2 hmin2(h2 a, h2 b) {
    return __builtin_elementwise_min(a, b);  // v_pk_min_f16
}

__device__ __forceinline__ h2 pkrtz(float a, float b) {
    auto r = __builtin_amdgcn_cvt_pkrtz(a, b);  // v_cvt_pkrtz_f16_f32
    return *reinterpret_cast<h2*>(&r);
}

// min over 12 half2 of (pr[k] - w[k]) for one weight row di; consumes the
// prefetch registers directly (SSA, no copies).
__device__ __forceinline__ h2 rowmin3(const float4* pr, const h2 w[3][4]) {
    h2 t[12];
#pragma unroll
    for (int dj = 0; dj < 3; ++dj) {
        const h2* p = reinterpret_cast<const h2*>(&pr[dj]);
#pragma unroll
        for (int q = 0; q < 4; ++q)
            t[dj * 4 + q] = p[q] - w[dj][q];  // v_pk_add_f16 neg
    }
#pragma unroll
    for (int k = 0; k < 6; ++k) t[k] = hmin2(t[k], t[k + 6]);
    t[0] = hmin2(t[0], t[3]);
    t[1] = hmin2(t[1], t[4]);
    t[2] = hmin2(t[2], t[5]);
    return hmin2(hmin2(t[0], t[1]), t[2]);
}

__global__ __launch_bounds__(512, 4) void erosion_kernel(
    const float* __restrict__ x, const float* __restrict__ Wt,
    float* __restrict__ out)
{
    __shared__ __align__(16) _Float16 tile[2 * TROWS * LROW];  // 7360 B
    __shared__ __align__(16) _Float16 wbuf[2 * 2304];          // 9216 B
    __shared__ __align__(16) _Float16 vm[TI * VROW];           // 22848 B

    const int tid = threadIdx.x;
    const int f  = tid & 31;
    const int ch = (tid >> 5) & 1;   // channel half: 0 -> c 0..7, 1 -> c 8..15
    const int jt = tid >> 6;         // column in block 0..7 (wave-uniform)
    const int b  = blockIdx.z;
    const int i0 = blockIdx.y * TI;
    const int jb = blockIdx.x * NCOL;

    // ---- stage x tile: fp32 -> fp16 LDS (23 rows x 10 cols x 2 ch) ----
    // 460 chunks, one per thread (52 threads idle).
    if (tid < TROWS * 2 * SCOL) {
        const float* xg = x + (size_t)b * (128 * 128 * 16);
        int r   = tid / (2 * SCOL);
        int k   = tid % (2 * SCOL);
        int cc  = k >> 1;               // 0..9 tile column
        int ch2 = k & 1;
        int col = min(jb + cc, 127);    // clamp: feeds never-stored outputs only
        const float* src = xg + ((size_t)(i0 + r) * 128 + col) * 16 + ch2 * 8;
        float4 lo = *reinterpret_cast<const float4*>(src);
        float4 hi = *reinterpret_cast<const float4*>(src + 4);
        h2 o[4] = { pkrtz(lo.x, lo.y), pkrtz(lo.z, lo.w),
                    pkrtz(hi.x, hi.y), pkrtz(hi.z, hi.w) };
        *reinterpret_cast<float4*>(
            &tile[ch2 * (TROWS * LROW) + r * LROW + cc * 8]) =
            *reinterpret_cast<float4*>(o);
    }

    // ---- stage W packed-h2: wl[g*32 + f] = {W[.,2c,f],W[.,2c+1,f]} ----
    // g = p*8 + cpair (p = di*3+dj, cpair = c/2); W flat idx = g*64 + f.
    // 2304 h2 tasks = 4.5 rounds of 512.
    {
        h2* wl = reinterpret_cast<h2*>(wbuf);
#pragma unroll
        for (int rr = 0; rr < 4; ++rr) {
            int t  = rr * 512 + tid;
            int g  = t >> 5;
            int ff = t & 31;
            wl[t] = pkrtz(Wt[g * 64 + ff], Wt[g * 64 + 32 + ff]);
        }
        if (tid < 2304 - 2048) {
            int t  = 2048 + tid;
            int g  = t >> 5;
            int ff = t & 31;
            wl[t] = pkrtz(Wt[g * 64 + ff], Wt[g * 64 + 32 + ff]);
        }
    }

    __syncthreads();   // barrier 1: tile + wbuf read-only from here on

    // ---- read this thread's W frags ONCE: 36 conflict-free ds_read_b32,
    // then value-capture through empty asm so LLVM cannot sink/remat the
    // LDS reads into the main loop (the R17 4x LDS-traffic bug). ----
    h2 wh[3][3][4];
    {
        const h2* wl = reinterpret_cast<const h2*>(wbuf);
#pragma unroll
        for (int p = 0; p < 9; ++p)
#pragma unroll
            for (int q = 0; q < 4; ++q) {
                unsigned u = __builtin_bit_cast(
                    unsigned, wl[(p * 8 + ch * 4 + q) * 32 + f]);
                asm("" : "+v"(u));   // opaque: forces VGPR residency
                wh[p / 3][p % 3][q] = __builtin_bit_cast(h2, u);
            }
    }

    const _Float16* lb = &tile[ch * (TROWS * LROW) + jt * 8];  // row 0, col jt

    // prime depth-1 prefetch regs
    float4 pre[3];
#pragma unroll
    for (int dj = 0; dj < 3; ++dj)
        pre[dj] = *reinterpret_cast<const float4*>(lb + dj * 8);

    const _Float16 HINF = (_Float16)__builtin_huge_valf();
    h2 accB = {HINF, HINF};  // partial min for output row r-1
    h2 accC = {HINF, HINF};  // partial min for output row r-2

    // vm slot for this thread: [row][jt][ch][f] with padded col stride
    _Float16* vslot = &vm[jt * VCOL + ch * 32 + f];

    auto body = [&](int r, bool do_prefetch, bool do_vm) {
        h2 n0 = rowmin3(pre, wh[0]);
        h2 n1 = rowmin3(pre, wh[1]);
        h2 n2 = rowmin3(pre, wh[2]);

        if (do_prefetch) {
            const _Float16* ln = lb + (r + 1) * LROW;
#pragma unroll
            for (int dj = 0; dj < 3; ++dj)
                pre[dj] = *reinterpret_cast<const float4*>(ln + dj * 8);
        }

        h2 fin2 = hmin2(accC, n2);  // output row r-2 complete (this ch-half)
        accC = hmin2(accB, n1);
        accB = n0;

        if (do_vm) {
            _Float16 a = fin2[0], c = fin2[1];
            _Float16 m = a < c ? a : c;          // v_min_f16
            vslot[(r - 2) * VROW] = m;           // full-wave b16 LDS write
        }
    };

    body(0, true, false);
    body(1, true, false);
#pragma unroll
    for (int r = 2; r < TROWS - 1; ++r)   // FULL unroll: r = 2..21 literal
        body(r, true, true);
    body(TROWS - 1, false, true);         // r = 22, no prefetch

    __syncthreads();   // barrier 2: vm complete

    // ---- merge epilogue: 1344 float4 tasks, 1KB contiguous per wave ----
    // task t: row = t>>6, k = t&63, col = k>>3, q = k&7.
    // partials: ch0 at vm[row*VROW + col*VCOL + 4q..+3], ch1 at +32.
    {
        float* outb = out + (size_t)b * (126 * 126 * 32);
        auto merge = [&](int t) {
            int row = t >> 6;
            int k   = t & 63;
            int col = k >> 3;
            int q   = k & 7;
            int jj  = jb + col;
            const _Float16* base = &vm[row * VROW + col * VCOL + q * 4];
            h2 a[2], c[2];
            *reinterpret_cast<double*>(a) = *reinterpret_cast<const double*>(base);
            *reinterpret_cast<double*>(c) = *reinterpret_cast<const double*>(base + 32);
            h2 m0 = hmin2(a[0], c[0]);
            h2 m1 = hmin2(a[1], c[1]);
            float4 o = { (float)m0[0], (float)m0[1], (float)m1[0], (float)m1[1] };
            if (jj < 126)
                *reinterpret_cast<float4*>(
                    &outb[((size_t)(i0 + row) * 126 + jj) * 32 + q * 4]) = o;
        };
        merge(tid);
        merge(tid + 512);
        if (tid < TI * 64 - 1024) merge(tid + 1024);  // 320 extra tasks
    }
}

extern "C" void kernel_launch(void* const* d_in, const int* in_sizes, int n_in,
                              void* d_out, int out_size, void* d_ws, size_t ws_size,
                              hipStream_t stream) {
    const float* x  = (const float*)d_in[0];  // 16*128*128*16
    const float* Wt = (const float*)d_in[1];  // 3*3*16*32
    float* out = (float*)d_out;               // 16*126*126*32

    dim3 grid(16, 6, 16);   // 1536 blocks, 8 output cols each
    dim3 block(512);
    erosion_kernel<<<grid, block, 0, stream>>>(x, Wt, out);
}